// Round 15
// baseline (42.855 us; speedup 1.0000x reference)
//
#include <hip/hip_runtime.h>
#include <hip/hip_bf16.h>
#include <math.h>

// Problem constants
#define CIN 64
#define CQK 8
#define BATCH 8
#define NPOS 4096   // H*W
#define TN 256      // n-tile (16 slots)
#define NT (NPOS / TN)

typedef __attribute__((ext_vector_type(8))) short s16x8;
typedef __attribute__((ext_vector_type(4))) float f32x4;
typedef __attribute__((ext_vector_type(16))) float f32x16;

#define Z16 {0,0,0,0,0,0,0,0,0,0,0,0,0,0,0,0}

// Schraudolph: scores arrive as y = s*2^23 + 127*2^23 from the MFMA
// (Q pre-scaled by log2e*2^23; C-operand = BIAS). p ~= bitcast(int(y)).
// The uniform approximation scale cancels in o = (P V) / rowsum(P).
#define SCH_BIAS 1065353216.0f   // 127 * 2^23

// single-instruction packed f32->bf16 (RNE) pair convert
__device__ inline unsigned cvt_pk_bf16(float lo, float hi) {
    unsigned r;
    asm("v_cvt_pk_bf16_f32 %0, %1, %2" : "=v"(r) : "v"(lo), "v"(hi));
    return r;
}
// Schraudolph exp2: y -> bitcast(int(y))  (1 VALU op)
__device__ inline float sch_exp(float y) {
    return __builtin_bit_cast(float, (int)y);
}

// ---------------------------------------------------------------------------
// Kernel 1: MFMA projections -> bf16 (round-11 structure, validated;
// Q scale = log2e*2^23 for the Schraudolph score domain). Unchanged.
// ---------------------------------------------------------------------------
__global__ __launch_bounds__(256) void proj_kernel(
    const float* __restrict__ x,
    const float* __restrict__ Wf, const float* __restrict__ bf,
    const float* __restrict__ Wg, const float* __restrict__ bg,
    const float* __restrict__ Wh, const float* __restrict__ bh,
    unsigned short* __restrict__ Kp, unsigned short* __restrict__ Qp,
    unsigned short* __restrict__ Vimg)
{
    __shared__ float xs[CIN * 34];   // 64c x 32n, stride 34 (frag reads 2/bank)
    __shared__ float bss[80];        // bf(8) | bg(8) | bh(64)

    const int tid = threadIdx.x;
    const int b   = blockIdx.y;
    const int n0  = blockIdx.x * 32;

    if (tid < 80)
        bss[tid] = (tid < 8) ? bf[tid] : (tid < 16) ? bg[tid - 8] : bh[tid - 16];

    // ---- stage x tile (64c x 32n f32) ----
    {
        const int c   = tid >> 2;
        const int seg = tid & 3;
        const float* src = x + ((size_t)(b * CIN + c)) * NPOS + n0 + seg * 8;
        float* dst = xs + c * 34 + seg * 8;
#pragma unroll
        for (int k = 0; k < 2; ++k) {
            const float4 v = *(const float4*)(src + k * 4);
            *(float2*)(dst + k * 4)     = make_float2(v.x, v.y);
            *(float2*)(dst + k * 4 + 2) = make_float2(v.z, v.w);
        }
    }

    const int l    = tid & 63;
    const int w    = tid >> 6;
    const int ng   = w >> 1;      // n-group (16 n)
    const int role = w & 1;       // 0: KQ+V01, 1: V23
    const int lm   = l & 15;
    const int h    = l >> 4;

    auto wfrag = [&](const float* Wrow) -> s16x8 {
        const float4 a  = *(const float4*)(Wrow);
        const float4 bq = *(const float4*)(Wrow + 4);
        union { unsigned u[4]; s16x8 v; } r;
        r.u[0] = cvt_pk_bf16(a.x, a.y);
        r.u[1] = cvt_pk_bf16(a.z, a.w);
        r.u[2] = cvt_pk_bf16(bq.x, bq.y);
        r.u[3] = cvt_pk_bf16(bq.z, bq.w);
        return r.v;
    };

    s16x8 wkq0 = {0,0,0,0,0,0,0,0}, wkq1 = {0,0,0,0,0,0,0,0};
    if (role == 0) {
        const float* kqrow = (lm < 8) ? (Wf + lm * CIN) : (Wg + (lm - 8) * CIN);
        wkq0 = wfrag(kqrow + h * 8);
        wkq1 = wfrag(kqrow + h * 8 + 32);
    }
    s16x8 wv0[2], wv1[2];
#pragma unroll
    for (int vt = 0; vt < 2; ++vt) {
        const float* vr = Wh + ((role * 2 + vt) * 16 + lm) * CIN + h * 8;
        wv0[vt] = wfrag(vr);
        wv1[vt] = wfrag(vr + 32);
    }

    __syncthreads();

    union { unsigned u[4]; s16x8 v; } xf0, xf1;
#pragma unroll
    for (int e2 = 0; e2 < 4; ++e2) {
        const int c = h * 8 + e2 * 2;
        xf0.u[e2] = cvt_pk_bf16(xs[c * 34 + ng * 16 + lm],
                                xs[(c + 1) * 34 + ng * 16 + lm]);
        xf1.u[e2] = cvt_pk_bf16(xs[(c + 32) * 34 + ng * 16 + lm],
                                xs[(c + 33) * 34 + ng * 16 + lm]);
    }

    const f32x4 z = {0.f, 0.f, 0.f, 0.f};
    f32x4 va[2];
#pragma unroll
    for (int vt = 0; vt < 2; ++vt) {
        va[vt] = __builtin_amdgcn_mfma_f32_16x16x32_bf16(xf0.v, wv0[vt], z, 0, 0, 0);
        va[vt] = __builtin_amdgcn_mfma_f32_16x16x32_bf16(xf1.v, wv1[vt], va[vt], 0, 0, 0);
    }

    const float QSCALE = 1.44269504088896f * 8388608.0f;   // log2e * 2^23

    if (role == 0) {
        f32x4 kq = __builtin_amdgcn_mfma_f32_16x16x32_bf16(wkq0, xf0.v, z, 0, 0, 0);
        kq = __builtin_amdgcn_mfma_f32_16x16x32_bf16(wkq1, xf1.v, kq, 0, 0, 0);
        const int n = n0 + ng * 16 + lm;
        float v0 = kq[0] + bss[h * 4 + 0];
        float v1 = kq[1] + bss[h * 4 + 1];
        float v2 = kq[2] + bss[h * 4 + 2];
        float v3 = kq[3] + bss[h * 4 + 3];
        if (h >= 2) { v0 *= QSCALE; v1 *= QSCALE; v2 *= QSCALE; v3 *= QSCALE; }
        uint2 pk;
        pk.x = cvt_pk_bf16(v0, v1);
        pk.y = cvt_pk_bf16(v2, v3);
        unsigned short* dstq =
            (h < 2 ? Kp : Qp) + ((size_t)(b * NPOS + n)) * CQK + (h & 1) * 4;
        *(uint2*)dstq = pk;
    }

    {
        const int t128 = n0 >> 7;
        const int sub  = (n0 & 127) >> 5;
        unsigned short* dstB =
            Vimg + ((size_t)(b * 32 + t128)) * 8192 + (size_t)sub * 2048;
        const int jj   = (h & 1) * 2 + ng;
        const int half = h >> 1;
#pragma unroll
        for (int vt = 0; vt < 2; ++vt) {
            const int C = (role * 2 + vt) * 16 + lm;
            const float bb = bss[16 + C];
            uint2 pk;
            pk.x = cvt_pk_bf16(va[vt][0] + bb, va[vt][1] + bb);
            pk.y = cvt_pk_bf16(va[vt][2] + bb, va[vt][3] + bb);
            const int p = ((jj & 1) * 2 + (C >> 5)) * 64 + (jj >> 1) * 32 + (C & 31);
            *(uint2*)(dstB + p * 8 + half * 4) = pk;
        }
    }
}

// ---------------------------------------------------------------------------
// Kernel 2: MFMA flash attention, no-max unnormalized Schraudolph softmax.
// ROUND 15: dependency-shape surgery on the r14 slot.
//  (a) all 4 score MFMAs (2 halves x 2 m-tiles) issued up front — each
//      covers the previous one's latency; half-1 cvt is independent VALU
//      the scheduler can slide under half-0's PV burst.
//  (b) PV MFMAs interleaved across the 4 accumulator chains (3 independent
//      MFMAs between dependent accumulates >= MFMA latency).
//  (c) s_setprio removed (phase-locked twin waves; m190: hurts lockstep).
// Slot: wait vmcnt(10) -> 4 score MFMA -> cvt h0 -> PV h0 (interleaved) ->
// cvt h1 -> PV h1 -> prefetch tile t+2 (2 K + 8 V coalesced 1KB loads).
// Grid 512 (b = id&7 XCD-pinned), 64 q/block, 2 waves/SIMD.
// ---------------------------------------------------------------------------
__global__ __launch_bounds__(256, 2) void attn_kernel(
    const unsigned short* __restrict__ Kp, const unsigned short* __restrict__ Qp,
    const unsigned short* __restrict__ Vimg, const float* __restrict__ x,
    const float* __restrict__ gamma, float* __restrict__ out)
{
    // epilogue only: 4 wave-regions x 64C x 36 f32 + rsl[4][64]
    __shared__ __align__(16) float smem[4 * 64 * 36 + 256];
    float* reg = smem;
    float* rsl = smem + 4 * 64 * 36;

    const int tid = threadIdx.x;
    const int l   = tid & 63;
    const int w   = tid >> 6;      // wave = 64-n substep owner
    const int lc  = l & 31;
    const int h   = l >> 5;
    const int id  = blockIdx.x;
    const int b   = id & 7;        // XCD-pinned batch
    const int m0  = (id >> 3) * 64;

    const unsigned short* Kbat = Kp + (size_t)b * NPOS * CQK;
    const char* Vbat = (const char*)(Vimg + (size_t)b * NPOS * CIN);

    // Q fragments (B operand): h=1 lanes (k=8..15) must be zero
    s16x8 qf0 = {0,0,0,0,0,0,0,0}, qf1 = {0,0,0,0,0,0,0,0};
    if (h == 0) {
        qf0 = *(const s16x8*)(Qp + ((size_t)(b * NPOS + m0 + lc)) * CQK);
        qf1 = *(const s16x8*)(Qp + ((size_t)(b * NPOS + m0 + 32 + lc)) * CQK);
    }

    f32x16 acc00 = Z16, acc01 = Z16, acc10 = Z16, acc11 = Z16;
    float rsum0 = 0.f, rsum1 = 0.f;
    const f32x16 bias16 = {SCH_BIAS, SCH_BIAS, SCH_BIAS, SCH_BIAS,
                           SCH_BIAS, SCH_BIAS, SCH_BIAS, SCH_BIAS,
                           SCH_BIAS, SCH_BIAS, SCH_BIAS, SCH_BIAS,
                           SCH_BIAS, SCH_BIAS, SCH_BIAS, SCH_BIAS};

    s16x8 vfA[8], vfB[8], kaA[2], kaB[2];

    // One tile = 10 loads, K first then V (order fixes vmcnt accounting).
    auto loadTile = [&](s16x8* vf, s16x8* ka, int t) {
        const char* kb = (const char*)(Kbat + ((size_t)(t * TN + w * 64 + lc)) * CQK);
        ka[0] = *(const s16x8*)kb;
        ka[1] = *(const s16x8*)(kb + 32 * 16);
        const char* base = Vbat + (size_t)t * 32768 + w * 8192 + l * 16;
#pragma unroll
        for (int c = 0; c < 8; ++c)
            vf[c] = *(const s16x8*)(base + c * 1024);
    };

    // Convert one 32x(32q) score tile to P fragments + rowsum contribution.
    struct pfrags { s16x8 p1, p2; };
    auto convert = [&](const f32x16& sc, float& rsum) -> pfrags {
        float p[16];
#pragma unroll
        for (int i = 0; i < 16; ++i) p[i] = sch_exp(sc[i]);
        union { unsigned u[4]; s16x8 v; } P1, P2;
#pragma unroll
        for (int i = 0; i < 4; ++i) {
            P1.u[i] = cvt_pk_bf16(p[2 * i],     p[2 * i + 1]);
            P2.u[i] = cvt_pk_bf16(p[8 + 2 * i], p[9 + 2 * i]);
        }
        rsum += (((p[0] + p[1]) + (p[2] + p[3])) +
                 ((p[4] + p[5]) + (p[6] + p[7]))) +
                (((p[8] + p[9]) + (p[10] + p[11])) +
                 ((p[12] + p[13]) + (p[14] + p[15])));
        return pfrags{P1.v, P2.v};
    };

    // PV for one half: interleaved across the 4 accumulator chains.
    auto pv = [&](const pfrags& fa, const pfrags& fb, const s16x8* vfh) {
        acc00 = __builtin_amdgcn_mfma_f32_32x32x16_bf16(fa.p1, vfh[0], acc00, 0, 0, 0);
        acc01 = __builtin_amdgcn_mfma_f32_32x32x16_bf16(fa.p1, vfh[1], acc01, 0, 0, 0);
        acc10 = __builtin_amdgcn_mfma_f32_32x32x16_bf16(fb.p1, vfh[0], acc10, 0, 0, 0);
        acc11 = __builtin_amdgcn_mfma_f32_32x32x16_bf16(fb.p1, vfh[1], acc11, 0, 0, 0);
        acc00 = __builtin_amdgcn_mfma_f32_32x32x16_bf16(fa.p2, vfh[2], acc00, 0, 0, 0);
        acc01 = __builtin_amdgcn_mfma_f32_32x32x16_bf16(fa.p2, vfh[3], acc01, 0, 0, 0);
        acc10 = __builtin_amdgcn_mfma_f32_32x32x16_bf16(fb.p2, vfh[2], acc10, 0, 0, 0);
        acc11 = __builtin_amdgcn_mfma_f32_32x32x16_bf16(fb.p2, vfh[3], acc11, 0, 0, 0);
    };

    // Slot: consume tile t (both halves), then prefetch t+2 into same regs.
    auto slot = [&](s16x8* vf, s16x8* ka, int t, int drain, int pf) {
        if (drain) asm volatile("s_waitcnt vmcnt(0)"  ::: "memory");
        else       asm volatile("s_waitcnt vmcnt(10)" ::: "memory");
        // all 4 score MFMAs up front (mutual latency cover)
        const f32x16 sA0 = __builtin_amdgcn_mfma_f32_32x32x16_bf16(ka[0], qf0, bias16, 0, 0, 0);
        const f32x16 sA1 = __builtin_amdgcn_mfma_f32_32x32x16_bf16(ka[0], qf1, bias16, 0, 0, 0);
        const f32x16 sB0 = __builtin_amdgcn_mfma_f32_32x32x16_bf16(ka[1], qf0, bias16, 0, 0, 0);
        const f32x16 sB1 = __builtin_amdgcn_mfma_f32_32x32x16_bf16(ka[1], qf1, bias16, 0, 0, 0);
        // half 0
        const pfrags fA0 = convert(sA0, rsum0);
        const pfrags fA1 = convert(sA1, rsum1);
        pv(fA0, fA1, vf);
        // half 1 (cvt independent of half-0 PV -> scheduler overlap)
        const pfrags fB0 = convert(sB0, rsum0);
        const pfrags fB1 = convert(sB1, rsum1);
        pv(fB0, fB1, vf + 4);
        if (pf) loadTile(vf, ka, t + 2);
    };

    // ---- prologue: tiles 0,1 in flight ----
    loadTile(vfA, kaA, 0);
    loadTile(vfB, kaB, 1);

    // ---- 16 slots, period-2 rotation; last two slots skip prefetch ----
#pragma unroll 1
    for (int i = 0; i < 7; ++i) {
        slot(vfA, kaA, 2 * i,     0, 1);
        slot(vfB, kaB, 2 * i + 1, 0, 1);
    }
    slot(vfA, kaA, 14, 0, 0);
    slot(vfB, kaB, 15, 1, 0);

    // ---- row-sum partials -> LDS (combine lane halves) ----
    rsum0 += __shfl_xor(rsum0, 32, 64);
    rsum1 += __shfl_xor(rsum1, 32, 64);
    if (h == 0) {
        rsl[w * 64 + lc]      = rsum0;
        rsl[w * 64 + 32 + lc] = rsum1;
    }

    // ---- two-phase epilogue: combine 4 wave partials + residual write ----
    const float gm = gamma[0];
    auto epi = [&](const f32x16& a0, const f32x16& a1, int mOff) {
#pragma unroll
        for (int rq = 0; rq < 4; ++rq) {
            const int mb = 8 * rq + 4 * h;
            const f32x4 q0 = {a0[4 * rq], a0[4 * rq + 1], a0[4 * rq + 2], a0[4 * rq + 3]};
            const f32x4 q1 = {a1[4 * rq], a1[4 * rq + 1], a1[4 * rq + 2], a1[4 * rq + 3]};
            *(f32x4*)(reg + w * 2304 + lc * 36 + mb)        = q0;  // C = lc
            *(f32x4*)(reg + w * 2304 + (32 + lc) * 36 + mb) = q1;  // C = 32+lc
        }
        __syncthreads();
        const int c  = tid >> 2;
        const int mq = tid & 3;
        const size_t base = ((size_t)(b * CIN + c)) * NPOS + m0 + mOff + mq * 8;
#pragma unroll
        for (int q4 = 0; q4 < 2; ++q4) {
            const float4 xv = *(const float4*)(x + base + q4 * 4);
            float4 o;
#pragma unroll
            for (int i = 0; i < 4; ++i) {
                const int ml = mq * 8 + q4 * 4 + i;
                const float rsum = (rsl[mOff + ml] + rsl[64 + mOff + ml]) +
                                   (rsl[128 + mOff + ml] + rsl[192 + mOff + ml]);
                const int oi = c * 36 + ml;
                const float os = (reg[oi] + reg[2304 + oi]) + (reg[4608 + oi] + reg[6912 + oi]);
                ((float*)&o)[i] = ((const float*)&xv)[i] + gm * os / rsum;
            }
            *(float4*)(out + base + q4 * 4) = o;
        }
        __syncthreads();
    };
    epi(acc00, acc01, 0);
    epi(acc10, acc11, 32);
}

extern "C" void kernel_launch(void* const* d_in, const int* in_sizes, int n_in,
                              void* d_out, int out_size, void* d_ws, size_t ws_size,
                              hipStream_t stream) {
    const float* x     = (const float*)d_in[0];
    const float* Wf    = (const float*)d_in[1];
    const float* bf    = (const float*)d_in[2];
    const float* Wg    = (const float*)d_in[3];
    const float* bg    = (const float*)d_in[4];
    const float* Wh    = (const float*)d_in[5];
    const float* bh    = (const float*)d_in[6];
    const float* gamma = (const float*)d_in[7];
    float* out = (float*)d_out;

    // ws (bf16): Kp (B*N*8) | Qp (B*N*8) | Vimg (B*N*64 image) = 5 MB
    unsigned short* Kp   = (unsigned short*)d_ws;
    unsigned short* Qp   = Kp + (size_t)BATCH * NPOS * CQK;
    unsigned short* Vimg = Qp + (size_t)BATCH * NPOS * CQK;

    dim3 pgrid(NPOS / 32, BATCH);
    proj_kernel<<<pgrid, 256, 0, stream>>>(x, Wf, bf, Wg, bg, Wh, bh, Kp, Qp, Vimg);

    attn_kernel<<<dim3(BATCH * NPOS / 64), 256, 0, stream>>>(Kp, Qp, Vimg, x, gamma, out);
}

// Round 16
// 36.986 us; speedup vs baseline: 1.1587x; 1.1587x over previous
//
#include <hip/hip_runtime.h>
#include <hip/hip_bf16.h>
#include <math.h>

// Problem constants
#define CIN 64
#define CQK 8
#define BATCH 8
#define NPOS 4096   // H*W
#define TN 256      // n-tile (16 slots)
#define NT (NPOS / TN)

typedef __attribute__((ext_vector_type(8))) short s16x8;
typedef __attribute__((ext_vector_type(4))) float f32x4;
typedef __attribute__((ext_vector_type(16))) float f32x16;

#define Z16 {0,0,0,0,0,0,0,0,0,0,0,0,0,0,0,0}

// Schraudolph: scores arrive as y = s*2^23 + 127*2^23 from the MFMA
// (Q pre-scaled by log2e*2^23; C-operand = BIAS). p ~= bitcast(int(y)).
// The uniform approximation scale cancels in o = (P V) / rowsum(P).
#define SCH_BIAS 1065353216.0f   // 127 * 2^23

// single-instruction packed f32->bf16 (RNE) pair convert
__device__ inline unsigned cvt_pk_bf16(float lo, float hi) {
    unsigned r;
    asm("v_cvt_pk_bf16_f32 %0, %1, %2" : "=v"(r) : "v"(lo), "v"(hi));
    return r;
}
// Schraudolph exp2: y -> bitcast(int(y))  (1 VALU op)
__device__ inline float sch_exp(float y) {
    return __builtin_bit_cast(float, (int)y);
}

// ---------------------------------------------------------------------------
// Kernel 1: MFMA projections -> bf16 (round-11 structure, validated;
// Q scale = log2e*2^23 for the Schraudolph score domain). Unchanged.
// ---------------------------------------------------------------------------
__global__ __launch_bounds__(256) void proj_kernel(
    const float* __restrict__ x,
    const float* __restrict__ Wf, const float* __restrict__ bf,
    const float* __restrict__ Wg, const float* __restrict__ bg,
    const float* __restrict__ Wh, const float* __restrict__ bh,
    unsigned short* __restrict__ Kp, unsigned short* __restrict__ Qp,
    unsigned short* __restrict__ Vimg)
{
    __shared__ float xs[CIN * 34];   // 64c x 32n, stride 34 (frag reads 2/bank)
    __shared__ float bss[80];        // bf(8) | bg(8) | bh(64)

    const int tid = threadIdx.x;
    const int b   = blockIdx.y;
    const int n0  = blockIdx.x * 32;

    if (tid < 80)
        bss[tid] = (tid < 8) ? bf[tid] : (tid < 16) ? bg[tid - 8] : bh[tid - 16];

    // ---- stage x tile (64c x 32n f32) ----
    {
        const int c   = tid >> 2;
        const int seg = tid & 3;
        const float* src = x + ((size_t)(b * CIN + c)) * NPOS + n0 + seg * 8;
        float* dst = xs + c * 34 + seg * 8;
#pragma unroll
        for (int k = 0; k < 2; ++k) {
            const float4 v = *(const float4*)(src + k * 4);
            *(float2*)(dst + k * 4)     = make_float2(v.x, v.y);
            *(float2*)(dst + k * 4 + 2) = make_float2(v.z, v.w);
        }
    }

    const int l    = tid & 63;
    const int w    = tid >> 6;
    const int ng   = w >> 1;      // n-group (16 n)
    const int role = w & 1;       // 0: KQ+V01, 1: V23
    const int lm   = l & 15;
    const int h    = l >> 4;

    auto wfrag = [&](const float* Wrow) -> s16x8 {
        const float4 a  = *(const float4*)(Wrow);
        const float4 bq = *(const float4*)(Wrow + 4);
        union { unsigned u[4]; s16x8 v; } r;
        r.u[0] = cvt_pk_bf16(a.x, a.y);
        r.u[1] = cvt_pk_bf16(a.z, a.w);
        r.u[2] = cvt_pk_bf16(bq.x, bq.y);
        r.u[3] = cvt_pk_bf16(bq.z, bq.w);
        return r.v;
    };

    s16x8 wkq0 = {0,0,0,0,0,0,0,0}, wkq1 = {0,0,0,0,0,0,0,0};
    if (role == 0) {
        const float* kqrow = (lm < 8) ? (Wf + lm * CIN) : (Wg + (lm - 8) * CIN);
        wkq0 = wfrag(kqrow + h * 8);
        wkq1 = wfrag(kqrow + h * 8 + 32);
    }
    s16x8 wv0[2], wv1[2];
#pragma unroll
    for (int vt = 0; vt < 2; ++vt) {
        const float* vr = Wh + ((role * 2 + vt) * 16 + lm) * CIN + h * 8;
        wv0[vt] = wfrag(vr);
        wv1[vt] = wfrag(vr + 32);
    }

    __syncthreads();

    union { unsigned u[4]; s16x8 v; } xf0, xf1;
#pragma unroll
    for (int e2 = 0; e2 < 4; ++e2) {
        const int c = h * 8 + e2 * 2;
        xf0.u[e2] = cvt_pk_bf16(xs[c * 34 + ng * 16 + lm],
                                xs[(c + 1) * 34 + ng * 16 + lm]);
        xf1.u[e2] = cvt_pk_bf16(xs[(c + 32) * 34 + ng * 16 + lm],
                                xs[(c + 33) * 34 + ng * 16 + lm]);
    }

    const f32x4 z = {0.f, 0.f, 0.f, 0.f};
    f32x4 va[2];
#pragma unroll
    for (int vt = 0; vt < 2; ++vt) {
        va[vt] = __builtin_amdgcn_mfma_f32_16x16x32_bf16(xf0.v, wv0[vt], z, 0, 0, 0);
        va[vt] = __builtin_amdgcn_mfma_f32_16x16x32_bf16(xf1.v, wv1[vt], va[vt], 0, 0, 0);
    }

    const float QSCALE = 1.44269504088896f * 8388608.0f;   // log2e * 2^23

    if (role == 0) {
        f32x4 kq = __builtin_amdgcn_mfma_f32_16x16x32_bf16(wkq0, xf0.v, z, 0, 0, 0);
        kq = __builtin_amdgcn_mfma_f32_16x16x32_bf16(wkq1, xf1.v, kq, 0, 0, 0);
        const int n = n0 + ng * 16 + lm;
        float v0 = kq[0] + bss[h * 4 + 0];
        float v1 = kq[1] + bss[h * 4 + 1];
        float v2 = kq[2] + bss[h * 4 + 2];
        float v3 = kq[3] + bss[h * 4 + 3];
        if (h >= 2) { v0 *= QSCALE; v1 *= QSCALE; v2 *= QSCALE; v3 *= QSCALE; }
        uint2 pk;
        pk.x = cvt_pk_bf16(v0, v1);
        pk.y = cvt_pk_bf16(v2, v3);
        unsigned short* dstq =
            (h < 2 ? Kp : Qp) + ((size_t)(b * NPOS + n)) * CQK + (h & 1) * 4;
        *(uint2*)dstq = pk;
    }

    {
        const int t128 = n0 >> 7;
        const int sub  = (n0 & 127) >> 5;
        unsigned short* dstB =
            Vimg + ((size_t)(b * 32 + t128)) * 8192 + (size_t)sub * 2048;
        const int jj   = (h & 1) * 2 + ng;
        const int half = h >> 1;
#pragma unroll
        for (int vt = 0; vt < 2; ++vt) {
            const int C = (role * 2 + vt) * 16 + lm;
            const float bb = bss[16 + C];
            uint2 pk;
            pk.x = cvt_pk_bf16(va[vt][0] + bb, va[vt][1] + bb);
            pk.y = cvt_pk_bf16(va[vt][2] + bb, va[vt][3] + bb);
            const int p = ((jj & 1) * 2 + (C >> 5)) * 64 + (jj >> 1) * 32 + (C & 31);
            *(uint2*)(dstB + p * 8 + half * 4) = pk;
        }
    }
}

// ---------------------------------------------------------------------------
// Kernel 2: MFMA flash attention, no-max unnormalized Schraudolph softmax.
// ROUND 16 = r14 (38.0us known-good) + two ZERO-REGISTER scheduling edits:
//  (1) PV MFMAs interleaved across the 4 accumulator chains
//      (acc00,acc01,acc10,acc11 | acc00,acc01,acc10,acc11): 3 independent
//      MFMAs between dependent accumulates >= MFMA latency.
//  (2) prefetch split mid-slot: {K0,V0..3}(t+2) after half-0 (source regs
//      dead), {K1,V4..7}(t+2) after half-1. Same K-first issue order per
//      group -> vmcnt(10) accounting unchanged (oldest 10 = tile t).
// Slot: wait vmcnt(10) -> half0 [2 score MFMA -> sch/cvt/rsum -> 8 PV] ->
// prefetch grp0 -> half1 -> prefetch grp1.
// Grid 512 (b = id&7 XCD-pinned), 64 q/block, 2 waves/SIMD.
// ---------------------------------------------------------------------------
__global__ __launch_bounds__(256, 2) void attn_kernel(
    const unsigned short* __restrict__ Kp, const unsigned short* __restrict__ Qp,
    const unsigned short* __restrict__ Vimg, const float* __restrict__ x,
    const float* __restrict__ gamma, float* __restrict__ out)
{
    // epilogue only: 4 wave-regions x 64C x 36 f32 + rsl[4][64]
    __shared__ __align__(16) float smem[4 * 64 * 36 + 256];
    float* reg = smem;
    float* rsl = smem + 4 * 64 * 36;

    const int tid = threadIdx.x;
    const int l   = tid & 63;
    const int w   = tid >> 6;      // wave = 64-n substep owner
    const int lc  = l & 31;
    const int h   = l >> 5;
    const int id  = blockIdx.x;
    const int b   = id & 7;        // XCD-pinned batch
    const int m0  = (id >> 3) * 64;

    const unsigned short* Kbat = Kp + (size_t)b * NPOS * CQK;
    const char* Vbat = (const char*)(Vimg + (size_t)b * NPOS * CIN);

    // Q fragments (B operand): h=1 lanes (k=8..15) must be zero
    s16x8 qf0 = {0,0,0,0,0,0,0,0}, qf1 = {0,0,0,0,0,0,0,0};
    if (h == 0) {
        qf0 = *(const s16x8*)(Qp + ((size_t)(b * NPOS + m0 + lc)) * CQK);
        qf1 = *(const s16x8*)(Qp + ((size_t)(b * NPOS + m0 + 32 + lc)) * CQK);
    }

    f32x16 acc00 = Z16, acc01 = Z16, acc10 = Z16, acc11 = Z16;
    float rsum0 = 0.f, rsum1 = 0.f;
    const f32x16 bias16 = {SCH_BIAS, SCH_BIAS, SCH_BIAS, SCH_BIAS,
                           SCH_BIAS, SCH_BIAS, SCH_BIAS, SCH_BIAS,
                           SCH_BIAS, SCH_BIAS, SCH_BIAS, SCH_BIAS,
                           SCH_BIAS, SCH_BIAS, SCH_BIAS, SCH_BIAS};

    s16x8 vfA[8], vfB[8], kaA[2], kaB[2];

    // Prefetch halves: group 0 = K row-half 0 + V[0..3]; group 1 = K1 + V[4..7].
    auto loadG0 = [&](s16x8* vf, s16x8* ka, int t) {
        const char* kb = (const char*)(Kbat + ((size_t)(t * TN + w * 64 + lc)) * CQK);
        ka[0] = *(const s16x8*)kb;
        const char* base = Vbat + (size_t)t * 32768 + w * 8192 + l * 16;
#pragma unroll
        for (int c = 0; c < 4; ++c)
            vf[c] = *(const s16x8*)(base + c * 1024);
    };
    auto loadG1 = [&](s16x8* vf, s16x8* ka, int t) {
        const char* kb = (const char*)(Kbat + ((size_t)(t * TN + w * 64 + lc)) * CQK);
        ka[1] = *(const s16x8*)(kb + 32 * 16);
        const char* base = Vbat + (size_t)t * 32768 + w * 8192 + l * 16;
#pragma unroll
        for (int c = 4; c < 8; ++c)
            vf[c] = *(const s16x8*)(base + c * 1024);
    };

    // Process one 32-n half: scores -> Schraudolph p -> rsum -> PV
    // (PV interleaved across the 4 accumulator chains).
    auto half_step = [&](const s16x8& kah, const s16x8* vfh) {
        f32x16 sc0 = __builtin_amdgcn_mfma_f32_32x32x16_bf16(kah, qf0, bias16, 0, 0, 0);
        f32x16 sc1 = __builtin_amdgcn_mfma_f32_32x32x16_bf16(kah, qf1, bias16, 0, 0, 0);
        float p0[16], p1[16];
#pragma unroll
        for (int i = 0; i < 16; ++i) {
            p0[i] = sch_exp(sc0[i]);
            p1[i] = sch_exp(sc1[i]);
        }
        union { unsigned u[4]; s16x8 v; } A1, A2, B1, B2;
#pragma unroll
        for (int i = 0; i < 4; ++i) {
            A1.u[i] = cvt_pk_bf16(p0[2 * i],     p0[2 * i + 1]);
            A2.u[i] = cvt_pk_bf16(p0[8 + 2 * i], p0[9 + 2 * i]);
            B1.u[i] = cvt_pk_bf16(p1[2 * i],     p1[2 * i + 1]);
            B2.u[i] = cvt_pk_bf16(p1[8 + 2 * i], p1[9 + 2 * i]);
        }
        rsum0 += (((p0[0] + p0[1]) + (p0[2] + p0[3])) +
                  ((p0[4] + p0[5]) + (p0[6] + p0[7]))) +
                 (((p0[8] + p0[9]) + (p0[10] + p0[11])) +
                  ((p0[12] + p0[13]) + (p0[14] + p0[15])));
        rsum1 += (((p1[0] + p1[1]) + (p1[2] + p1[3])) +
                  ((p1[4] + p1[5]) + (p1[6] + p1[7]))) +
                 (((p1[8] + p1[9]) + (p1[10] + p1[11])) +
                  ((p1[12] + p1[13]) + (p1[14] + p1[15])));
        // interleaved PV: 3 independent MFMAs between dependent accumulates
        acc00 = __builtin_amdgcn_mfma_f32_32x32x16_bf16(A1.v, vfh[0], acc00, 0, 0, 0);
        acc01 = __builtin_amdgcn_mfma_f32_32x32x16_bf16(A1.v, vfh[1], acc01, 0, 0, 0);
        acc10 = __builtin_amdgcn_mfma_f32_32x32x16_bf16(B1.v, vfh[0], acc10, 0, 0, 0);
        acc11 = __builtin_amdgcn_mfma_f32_32x32x16_bf16(B1.v, vfh[1], acc11, 0, 0, 0);
        acc00 = __builtin_amdgcn_mfma_f32_32x32x16_bf16(A2.v, vfh[2], acc00, 0, 0, 0);
        acc01 = __builtin_amdgcn_mfma_f32_32x32x16_bf16(A2.v, vfh[3], acc01, 0, 0, 0);
        acc10 = __builtin_amdgcn_mfma_f32_32x32x16_bf16(B2.v, vfh[2], acc10, 0, 0, 0);
        acc11 = __builtin_amdgcn_mfma_f32_32x32x16_bf16(B2.v, vfh[3], acc11, 0, 0, 0);
    };

    // Slot: consume tile t (both halves); prefetch t+2 split mid/end.
    auto slot = [&](s16x8* vf, s16x8* ka, int t, int drain, int pf) {
        if (drain) asm volatile("s_waitcnt vmcnt(0)"  ::: "memory");
        else       asm volatile("s_waitcnt vmcnt(10)" ::: "memory");
        __builtin_amdgcn_s_setprio(1);
        half_step(ka[0], vf);
        __builtin_amdgcn_s_setprio(0);
        if (pf) loadG0(vf, ka, t + 2);
        __builtin_amdgcn_s_setprio(1);
        half_step(ka[1], vf + 4);
        __builtin_amdgcn_s_setprio(0);
        if (pf) loadG1(vf, ka, t + 2);
    };

    // ---- prologue: tiles 0,1 in flight ----
    loadG0(vfA, kaA, 0); loadG1(vfA, kaA, 0);
    loadG0(vfB, kaB, 1); loadG1(vfB, kaB, 1);

    // ---- 16 slots, period-2 rotation; last two slots skip prefetch ----
#pragma unroll 1
    for (int i = 0; i < 7; ++i) {
        slot(vfA, kaA, 2 * i,     0, 1);
        slot(vfB, kaB, 2 * i + 1, 0, 1);
    }
    slot(vfA, kaA, 14, 0, 0);
    slot(vfB, kaB, 15, 1, 0);

    // ---- row-sum partials -> LDS (combine lane halves) ----
    rsum0 += __shfl_xor(rsum0, 32, 64);
    rsum1 += __shfl_xor(rsum1, 32, 64);
    if (h == 0) {
        rsl[w * 64 + lc]      = rsum0;
        rsl[w * 64 + 32 + lc] = rsum1;
    }

    // ---- two-phase epilogue: combine 4 wave partials + residual write ----
    const float gm = gamma[0];
    auto epi = [&](const f32x16& a0, const f32x16& a1, int mOff) {
#pragma unroll
        for (int rq = 0; rq < 4; ++rq) {
            const int mb = 8 * rq + 4 * h;
            const f32x4 q0 = {a0[4 * rq], a0[4 * rq + 1], a0[4 * rq + 2], a0[4 * rq + 3]};
            const f32x4 q1 = {a1[4 * rq], a1[4 * rq + 1], a1[4 * rq + 2], a1[4 * rq + 3]};
            *(f32x4*)(reg + w * 2304 + lc * 36 + mb)        = q0;  // C = lc
            *(f32x4*)(reg + w * 2304 + (32 + lc) * 36 + mb) = q1;  // C = 32+lc
        }
        __syncthreads();
        const int c  = tid >> 2;
        const int mq = tid & 3;
        const size_t base = ((size_t)(b * CIN + c)) * NPOS + m0 + mOff + mq * 8;
#pragma unroll
        for (int q4 = 0; q4 < 2; ++q4) {
            const float4 xv = *(const float4*)(x + base + q4 * 4);
            float4 o;
#pragma unroll
            for (int i = 0; i < 4; ++i) {
                const int ml = mq * 8 + q4 * 4 + i;
                const float rsum = (rsl[mOff + ml] + rsl[64 + mOff + ml]) +
                                   (rsl[128 + mOff + ml] + rsl[192 + mOff + ml]);
                const int oi = c * 36 + ml;
                const float os = (reg[oi] + reg[2304 + oi]) + (reg[4608 + oi] + reg[6912 + oi]);
                ((float*)&o)[i] = ((const float*)&xv)[i] + gm * os / rsum;
            }
            *(float4*)(out + base + q4 * 4) = o;
        }
        __syncthreads();
    };
    epi(acc00, acc01, 0);
    epi(acc10, acc11, 32);
}

extern "C" void kernel_launch(void* const* d_in, const int* in_sizes, int n_in,
                              void* d_out, int out_size, void* d_ws, size_t ws_size,
                              hipStream_t stream) {
    const float* x     = (const float*)d_in[0];
    const float* Wf    = (const float*)d_in[1];
    const float* bf    = (const float*)d_in[2];
    const float* Wg    = (const float*)d_in[3];
    const float* bg    = (const float*)d_in[4];
    const float* Wh    = (const float*)d_in[5];
    const float* bh    = (const float*)d_in[6];
    const float* gamma = (const float*)d_in[7];
    float* out = (float*)d_out;

    // ws (bf16): Kp (B*N*8) | Qp (B*N*8) | Vimg (B*N*64 image) = 5 MB
    unsigned short* Kp   = (unsigned short*)d_ws;
    unsigned short* Qp   = Kp + (size_t)BATCH * NPOS * CQK;
    unsigned short* Vimg = Qp + (size_t)BATCH * NPOS * CQK;

    dim3 pgrid(NPOS / 32, BATCH);
    proj_kernel<<<pgrid, 256, 0, stream>>>(x, Wf, bf, Wg, bg, Wh, bh, Kp, Qp, Vimg);

    attn_kernel<<<dim3(BATCH * NPOS / 64), 256, 0, stream>>>(Kp, Qp, Vimg, x, gamma, out);
}